// Round 14
// baseline (317.500 us; speedup 1.0000x reference)
//
#include <hip/hip_runtime.h>
#include <cstddef>

// ---------------------------------------------------------------------------
// GCN forward: 3 x ( h@W bf16 MFMA -> packed-bf16 xw -> CSR segsum+LN(+ReLU) )
// N=50000, E=800000, D: 128 -> 128 -> 128 -> 64.
// R26 = R15-exact structure (best verified 189us) + EDGE-LIST RANGE SORT:
//  - R21 datum: removing a dispatch boundary = +-0 -> boundary theory dead.
//  - Remaining signal: aggs at 4.3TB/s effective scatter, FETCH 76MB (37%
//    L2 miss) because xw-row reuses (avg 16x) are scattered in time over a
//    12.8MB working set vs 4MB per-XCD L2.
//  - Fix: per-node bucket-reorder of col lists (25 buckets, 2048 nodes each
//    ~0.5MB xw slice). All waves sweep xw in phase -> reuses cluster in time
//    -> ~1 miss + 15 L2 hits per row. Sum is commutative; order is free.
//  - Prepass folded into cvt_w dispatch (blocks 48+): 5 dispatches like R15.
//  - agg bodies byte-identical to R15, reading col2.
// (R27 resubmission: R26 never ran -- GPU acquisition timeout.)
// ---------------------------------------------------------------------------

typedef __attribute__((ext_vector_type(8))) short bf16x8;
typedef __attribute__((ext_vector_type(4))) float floatx4;
typedef __attribute__((ext_vector_type(4))) unsigned int uintx4;
typedef __attribute__((ext_vector_type(2))) unsigned int uintx2;

static __device__ __forceinline__ unsigned int f2bf(float f) {
    union { float f; unsigned int u; } v; v.f = f;
    unsigned int u = v.u;
    u += 0x7fffu + ((u >> 16) & 1u);
    return u >> 16;
}
static __device__ __forceinline__ float bf_lo(unsigned int p) {
    union { unsigned int u; float f; } v; v.u = p << 16; return v.f;
}
static __device__ __forceinline__ float bf_hi(unsigned int p) {
    union { unsigned int u; float f; } v; v.u = p & 0xffff0000u; return v.f;
}
static __device__ __forceinline__ void acc8(float* a, uintx4 v) {
    a[0] += bf_lo(v.x); a[1] += bf_hi(v.x);
    a[2] += bf_lo(v.y); a[3] += bf_hi(v.y);
    a[4] += bf_lo(v.z); a[5] += bf_hi(v.z);
    a[6] += bf_lo(v.w); a[7] += bf_hi(v.w);
}
static __device__ __forceinline__ void acc4(float* a, uintx2 v) {
    a[0] += bf_lo(v.x); a[1] += bf_hi(v.x);
    a[2] += bf_lo(v.y); a[3] += bf_hi(v.y);
}

// ---- dispatch 1: W cvt (blocks 0..47) + per-node col range-sort (48+) ------
__global__ __launch_bounds__(256) void cvt_sort(const float* __restrict__ W0,
                                                const float* __restrict__ W1,
                                                const float* __restrict__ W2,
                                                unsigned int* __restrict__ WtF,
                                                const int* __restrict__ ptr,
                                                const int* __restrict__ col,
                                                int* __restrict__ col2,
                                                int N) {
    if (blockIdx.x < 48) {
        const int m = blockIdx.x >> 4;
        const int slice = blockIdx.x & 15;
        const float* W = (m == 0) ? W0 : (m == 1) ? W1 : W2;
        const int ncols = (m == 2) ? 64 : 128;
        unsigned int* dst = WtF + m * 128 * 64;
        const int total = ncols * 64;                  // uints
        for (int idx = slice * 256 + threadIdx.x; idx < total; idx += 16 * 256) {
            const int j    = idx & 3;
            const int lane = (idx >> 2) & 63;
            const int s    = (idx >> 8) & 3;
            const int t    = idx >> 10;
            const int mcol = lane & 15;
            const int quad = lane >> 4;
            const int n = t * 16 + mcol;
            const int k = s * 32 + quad * 8 + 2 * j;
            unsigned int lo = f2bf(W[(size_t)k * ncols + n]);
            unsigned int hi = f2bf(W[(size_t)(k + 1) * ncols + n]);
            dst[idx] = (hi << 16) | lo;
        }
    } else {
        // bucket-reorder one node's edge list per thread (stable by bucket)
        const int node = (blockIdx.x - 48) * 256 + threadIdx.x;
        if (node < N) {
            const int s = ptr[node];
            const int e = ptr[node + 1];
            int pos = s;
            for (int b = 0; b < 25; ++b) {           // col>>11: 0..24 for col<50000
                for (int i = s; i < e; ++i) {
                    const int c = col[i];
                    if ((c >> 11) == b) col2[pos++] = c;
                }
            }
        }
    }
}

// ---- dispatch 2: bf16 MFMA GEMM, 1 wave per block (16 rows x NCOLS) --------
// Layer 0 only: A fp32 row-major (feat), in-register bf16 convert.
template <int NCOLS, bool A_FP32>
__global__ __launch_bounds__(64) void gemm_mfma(const void* __restrict__ Av,
                                                const unsigned int* __restrict__ Wt,
                                                unsigned int* __restrict__ C,
                                                int M) {
    const int lane = threadIdx.x;
    const int row0 = blockIdx.x * 16;
    const int quad = lane >> 4;
    const int mcol = lane & 15;

    constexpr int NT = NCOLS / 16;
    floatx4 acc[NT];
    #pragma unroll
    for (int t = 0; t < NT; ++t) acc[t] = (floatx4){0.f, 0.f, 0.f, 0.f};

    int aidx = row0 + mcol; if (aidx >= M) aidx = M - 1;
    const float*        arowF = (const float*)Av + (size_t)aidx * 128 + quad * 8;
    const unsigned int* bbase = Wt + lane * 4;

    #pragma unroll
    for (int s = 0; s < 4; ++s) {
        float4 fa = *(const float4*)(arowF + s * 32);
        float4 fb = *(const float4*)(arowF + s * 32 + 4);
        uintx4 ap;
        ap.x = (f2bf(fa.y) << 16) | f2bf(fa.x);
        ap.y = (f2bf(fa.w) << 16) | f2bf(fa.z);
        ap.z = (f2bf(fb.y) << 16) | f2bf(fb.x);
        ap.w = (f2bf(fb.w) << 16) | f2bf(fb.z);
        bf16x8 a = __builtin_bit_cast(bf16x8, ap);
        #pragma unroll
        for (int t = 0; t < NT; ++t) {
            uintx4 bp = *(const uintx4*)(bbase + t * 1024 + s * 256);
            bf16x8 b = __builtin_bit_cast(bf16x8, bp);
            acc[t] = __builtin_amdgcn_mfma_f32_16x16x32_bf16(a, b, acc[t], 0, 0, 0);
        }
    }

    const int rowStride = NCOLS >> 1;
    #pragma unroll
    for (int t = 0; t < NT; ++t) {
        #pragma unroll
        for (int r = 0; r < 4; ++r) {
            unsigned int mybf = f2bf(acc[t][r]);
            unsigned int pair = __shfl_xor(mybf, 1, 64);
            int orow = row0 + quad * 4 + r;
            if (orow < M && (mcol & 1) == 0) {
                unsigned int packed = (pair << 16) | mybf;
                C[(size_t)orow * rowStride + t * 8 + (mcol >> 1)] = packed;
            }
        }
    }
}

// ---- dispatches 3,4: CSR segsum + LN + ReLU -> LDS A-tile -> MFMA x W ------
// R15 body, unchanged (2-deep pipelined concurrent gather), reads col2.
template <int NCOLS_OUT>
__global__ __launch_bounds__(256) void agg_gemm(const unsigned int* __restrict__ xw,
                                                const int* __restrict__ ptr,
                                                const int* __restrict__ col,
                                                const unsigned int* __restrict__ Wt,
                                                unsigned int* __restrict__ C,
                                                int N, int Emax /* = E-1 */) {
    __shared__ unsigned int lds[1024];           // 16 rows x 128 bf16, A-frag order
    const int tile = blockIdx.x;
    const int wave = threadIdx.x >> 6;
    const int lane = threadIdx.x & 63;
    const int g  = lane >> 4;     // 0..3 edge group
    const int sl = lane & 15;     // 0..15 sublane (owns 8 features)

    int s0[4], len[4];
    int maxlen = 0;
    #pragma unroll
    for (int n = 0; n < 4; ++n) {
        const int node = tile * 16 + wave * 4 + n;
        const int nc = node < N ? node : N - 1;
        const int a = ptr[nc];
        const int b = node < N ? ptr[nc + 1] : a;
        s0[n] = a; len[n] = b - a;
        maxlen = max(maxlen, len[n]);
    }

    float acc[4][8] = {};
    const unsigned int* base = xw + sl * 4;

    if (maxlen > 0) {
        #define LOADCOL(dst, OFF)                                            \
            _Pragma("unroll")                                                \
            for (int n = 0; n < 4; ++n) {                                    \
                int idx = (OFF) + g;                                         \
                idx = idx < len[n] ? idx : 0;                                \
                int ei = s0[n] + idx;                                        \
                ei = ei < Emax ? ei : Emax;                                  \
                dst[n] = col[ei];                                            \
            }
        #define GATHER4(dst, c)                                              \
            _Pragma("unroll")                                                \
            for (int n = 0; n < 4; ++n)                                      \
                dst[n] = *(const uintx4*)(base + (size_t)c[n] * 64);
        #define ACCUM4(v, OFF)                                               \
            _Pragma("unroll")                                                \
            for (int n = 0; n < 4; ++n)                                      \
                if ((OFF) + g < len[n]) acc8(acc[n], v[n]);

        int cA[4], cB[4], cC[4], cD[4];
        uintx4 vA[4], vB[4];
        LOADCOL(cA, 0)
        LOADCOL(cB, 4)
        GATHER4(vA, cA)
        LOADCOL(cC, 8)
        GATHER4(vB, cB)
        LOADCOL(cD, 12)

        const int rounds = (maxlen + 7) & ~7;
        for (int off = 0; off < rounds; off += 8) {
            ACCUM4(vA, off)
            GATHER4(vA, cC)            // data for off+8
            LOADCOL(cC, off + 16)
            ACCUM4(vB, off + 4)
            GATHER4(vB, cD)            // data for off+12
            LOADCOL(cD, off + 20)
        }
        #undef LOADCOL
        #undef GATHER4
        #undef ACCUM4
    }

    // ---- LN + ReLU per node, write LDS A-frag tile ----
    #pragma unroll
    for (int n = 0; n < 4; ++n) {
        const int m = wave * 4 + n;
        float a8[8];
        #pragma unroll
        for (int j = 0; j < 8; ++j) {
            float t = acc[n][j];
            t += __shfl_xor(t, 16, 64);
            t += __shfl_xor(t, 32, 64);
            a8[j] = t;
        }
        float s1 = 0.f, s2 = 0.f;
        #pragma unroll
        for (int j = 0; j < 8; ++j) { s1 += a8[j]; s2 += a8[j] * a8[j]; }
        #pragma unroll
        for (int mm = 8; mm >= 1; mm >>= 1) {
            s1 += __shfl_xor(s1, mm, 64);
            s2 += __shfl_xor(s2, mm, 64);
        }
        const float mean = s1 * (1.0f / 128.0f);
        const float var  = s2 * (1.0f / 128.0f) - mean * mean;
        const float inv  = rsqrtf(var + 1e-5f);

        if (g == 0) {
            float o[8];
            #pragma unroll
            for (int j = 0; j < 8; ++j)
                o[j] = fmaxf((a8[j] - mean) * inv, 0.f);
            uintx4 p;
            p.x = (f2bf(o[1]) << 16) | f2bf(o[0]);
            p.y = (f2bf(o[3]) << 16) | f2bf(o[2]);
            p.z = (f2bf(o[5]) << 16) | f2bf(o[4]);
            p.w = (f2bf(o[7]) << 16) | f2bf(o[6]);
            *(uintx4*)(lds + (sl >> 2) * 256 + (sl & 3) * 64 + m * 4) = p;
        }
    }
    __syncthreads();

    // ---- phase 2: 16 x NCOLS_OUT MFMA, wave covers NCOLS_OUT/4 cols --------
    constexpr int WT = NCOLS_OUT / 64;           // tiles per wave (2 or 1)
    const int quad = lane >> 4;
    const int mcol = lane & 15;
    floatx4 macc[WT];
    #pragma unroll
    for (int t = 0; t < WT; ++t) macc[t] = (floatx4){0.f, 0.f, 0.f, 0.f};

    const unsigned int* bbase = Wt + lane * 4;
    #pragma unroll
    for (int s4 = 0; s4 < 4; ++s4) {
        uintx4 ap = *(const uintx4*)(lds + s4 * 256 + lane * 4);
        bf16x8 a = __builtin_bit_cast(bf16x8, ap);
        #pragma unroll
        for (int tt = 0; tt < WT; ++tt) {
            const int t = wave * WT + tt;
            uintx4 bp = *(const uintx4*)(bbase + t * 1024 + s4 * 256);
            bf16x8 b = __builtin_bit_cast(bf16x8, bp);
            macc[tt] = __builtin_amdgcn_mfma_f32_16x16x32_bf16(a, b, macc[tt], 0, 0, 0);
        }
    }

    const int rowStride = NCOLS_OUT >> 1;
    #pragma unroll
    for (int tt = 0; tt < WT; ++tt) {
        const int t = wave * WT + tt;
        #pragma unroll
        for (int r = 0; r < 4; ++r) {
            unsigned int mybf = f2bf(macc[tt][r]);
            unsigned int pair = __shfl_xor(mybf, 1, 64);
            const int orow = tile * 16 + quad * 4 + r;
            if (orow < N && (mcol & 1) == 0) {
                unsigned int packed = (pair << 16) | mybf;
                C[(size_t)orow * rowStride + t * 8 + (mcol >> 1)] = packed;
            }
        }
    }
}

// ---- dispatch 5: CSR segsum + LN, D=64, fp32 out, no ReLU (R15 body) -------
__global__ __launch_bounds__(256) void agg_ln64(const unsigned int* __restrict__ xw,
                                                const int* __restrict__ ptr,
                                                const int* __restrict__ col,
                                                float* __restrict__ out,
                                                int N, int Emax) {
    const int tile = blockIdx.x;
    const int wave = threadIdx.x >> 6;
    const int lane = threadIdx.x & 63;
    const int g  = lane >> 4;     // 0..3 edge group
    const int sl = lane & 15;     // 0..15 sublane (owns 4 features)

    int s0[4], len[4];
    int maxlen = 0;
    #pragma unroll
    for (int n = 0; n < 4; ++n) {
        const int node = tile * 16 + wave * 4 + n;
        const int nc = node < N ? node : N - 1;
        const int a = ptr[nc];
        const int b = node < N ? ptr[nc + 1] : a;
        s0[n] = a; len[n] = b - a;
        maxlen = max(maxlen, len[n]);
    }

    float acc[4][4] = {};
    const unsigned int* base = xw + sl * 2;

    if (maxlen > 0) {
        #define LOADCOL(dst, OFF)                                            \
            _Pragma("unroll")                                                \
            for (int n = 0; n < 4; ++n) {                                    \
                int idx = (OFF) + g;                                         \
                idx = idx < len[n] ? idx : 0;                                \
                int ei = s0[n] + idx;                                        \
                ei = ei < Emax ? ei : Emax;                                  \
                dst[n] = col[ei];                                            \
            }
        #define GATHER2(dst, c)                                              \
            _Pragma("unroll")                                                \
            for (int n = 0; n < 4; ++n)                                      \
                dst[n] = *(const uintx2*)(base + (size_t)c[n] * 32);
        #define ACCUM2(v, OFF)                                               \
            _Pragma("unroll")                                                \
            for (int n = 0; n < 4; ++n)                                      \
                if ((OFF) + g < len[n]) acc4(acc[n], v[n]);

        int cA[4], cB[4], cC[4], cD[4];
        uintx2 vA[4], vB[4];
        LOADCOL(cA, 0)
        LOADCOL(cB, 4)
        GATHER2(vA, cA)
        LOADCOL(cC, 8)
        GATHER2(vB, cB)
        LOADCOL(cD, 12)

        const int rounds = (maxlen + 7) & ~7;
        for (int off = 0; off < rounds; off += 8) {
            ACCUM2(vA, off)
            GATHER2(vA, cC)
            LOADCOL(cC, off + 16)
            ACCUM2(vB, off + 4)
            GATHER2(vB, cD)
            LOADCOL(cD, off + 20)
        }
        #undef LOADCOL
        #undef GATHER2
        #undef ACCUM2
    }

    #pragma unroll
    for (int n = 0; n < 4; ++n) {
        const int node = tile * 16 + wave * 4 + n;
        float a4[4];
        #pragma unroll
        for (int j = 0; j < 4; ++j) {
            float t = acc[n][j];
            t += __shfl_xor(t, 16, 64);
            t += __shfl_xor(t, 32, 64);
            a4[j] = t;
        }
        float s1 = 0.f, s2 = 0.f;
        #pragma unroll
        for (int j = 0; j < 4; ++j) { s1 += a4[j]; s2 += a4[j] * a4[j]; }
        #pragma unroll
        for (int mm = 8; mm >= 1; mm >>= 1) {
            s1 += __shfl_xor(s1, mm, 64);
            s2 += __shfl_xor(s2, mm, 64);
        }
        const float mean = s1 * (1.0f / 64.0f);
        const float var  = s2 * (1.0f / 64.0f) - mean * mean;
        const float inv  = rsqrtf(var + 1e-5f);

        if (g == 0 && node < N) {
            float4 o;
            o.x = (a4[0] - mean) * inv;
            o.y = (a4[1] - mean) * inv;
            o.z = (a4[2] - mean) * inv;
            o.w = (a4[3] - mean) * inv;
            *(float4*)(out + (size_t)node * 64 + sl * 4) = o;
        }
    }
}

extern "C" void kernel_launch(void* const* d_in, const int* in_sizes, int n_in,
                              void* d_out, int out_size, void* d_ws, size_t ws_size,
                              hipStream_t stream) {
    const float* feat = (const float*)d_in[0];   // [N,128]
    const float* W0   = (const float*)d_in[1];   // [128,128]
    const float* W1   = (const float*)d_in[2];   // [128,128]
    const float* W2   = (const float*)d_in[3];   // [128,64]
    const int*   ptr  = (const int*)d_in[4];     // [N+1]
    const int*   col  = (const int*)d_in[5];     // [E]
    // d_in[6] = edge_rows, unused (CSR ptr encodes the same segments)

    const int N = in_sizes[4] - 1;               // 50000 (= 3125 * 16)
    const int E = in_sizes[5];                   // 800000
    const int Emax = E - 1;

    unsigned int* buf0 = (unsigned int*)d_ws;                // [N,64] uint, row-major packed
    unsigned int* buf1 = buf0 + (size_t)N * 64;              // [N,64] uint, row-major packed
    unsigned int* WtP  = buf1 + (size_t)N * 64;              // 3 x frag-ordered W
    int*          col2 = (int*)(WtP + 3 * 128 * 64);         // range-sorted edge lists
    float*        out  = (float*)d_out;                      // [N,64]

    const int tiles = (N + 15) / 16;             // 3125 (16-node tiles)
    const int sortBlocks = (N + 255) / 256;      // 196

    // Dispatch 1: W cvt + per-node col range-sort
    cvt_sort<<<48 + sortBlocks, 256, 0, stream>>>(W0, W1, W2, WtP, ptr, col, col2, N);
    // Dispatch 2: layer-0 GEMM (fp32 feat A-path)
    gemm_mfma<128, true><<<tiles, 64, 0, stream>>>(feat, WtP, buf0, N);
    // Dispatch 3: layer-0 agg+LN+ReLU fused with layer-1 GEMM
    agg_gemm<128><<<tiles, 256, 0, stream>>>(buf0, ptr, col2, WtP + 128 * 64, buf1, N, Emax);
    // Dispatch 4: layer-1 agg+LN+ReLU fused with layer-2 GEMM (D_out=64)
    agg_gemm<64><<<tiles, 256, 0, stream>>>(buf1, ptr, col2, WtP + 2 * 128 * 64, buf0, N, Emax);
    // Dispatch 5: layer-2 agg+LN (no ReLU), fp32 out
    agg_ln64<<<tiles, 256, 0, stream>>>(buf0, ptr, col2, out, N, Emax);
}

// Round 19
// 250.044 us; speedup vs baseline: 1.2698x; 1.2698x over previous
//
#include <hip/hip_runtime.h>
#include <cstddef>

// ---------------------------------------------------------------------------
// GCN forward: 3 x ( h@W bf16 MFMA -> packed-bf16 xw -> CSR segsum+LN(+ReLU) )
// N=50000, E=800000, D: 128 -> 128 -> 128 -> 64.
// R28 = R15 structure + FEATURE-QUARTERED xw (L2-capacity fix):
//  - R26 datum: per-node edge sort = null on aggs -> not an ordering problem.
//    FETCH 76MB/agg = ~6 L3-fetches per xw row per XCD = L2 CAPACITY misses
//    (12.8MB working set vs 4MB per-XCD L2).
//  - Fix: xw stored as 4 feature-quarters [4][N][32bf16] (3.2MB/slice < 4MB).
//    Agg gather loop runs 4x (once per quarter), each lane loads 1 uint (4B)
//    instead of uintx4: same lane map, same acc[4][8], same stats/MFMA phase.
//  - Producers write quartered: uint-in-row idx -> [idx>>4][row][idx&15].
//  - A-tile write remap: lane (g,sl) packs features g*32+sl*2,+1 at
//    lds[g*256+(sl>>2)*64+m*4+(sl&3)] (all 64 lanes, 1 uint per node).
//  - agg_ln64: 2 half passes, float2 out writes (h=g<2).
// (R32 resubmission: R28..R31 never ran -- infra failures. Hedge rule: if
//  container-failure mode repeats, next round reverts to known-good R15 to
//  disambiguate kernel-vs-infra.)
// ---------------------------------------------------------------------------

typedef __attribute__((ext_vector_type(8))) short bf16x8;
typedef __attribute__((ext_vector_type(4))) float floatx4;
typedef __attribute__((ext_vector_type(4))) unsigned int uintx4;

static __device__ __forceinline__ unsigned int f2bf(float f) {
    union { float f; unsigned int u; } v; v.f = f;
    unsigned int u = v.u;
    u += 0x7fffu + ((u >> 16) & 1u);
    return u >> 16;
}
static __device__ __forceinline__ float bf_lo(unsigned int p) {
    union { unsigned int u; float f; } v; v.u = p << 16; return v.f;
}
static __device__ __forceinline__ float bf_hi(unsigned int p) {
    union { unsigned int u; float f; } v; v.u = p & 0xffff0000u; return v.f;
}

// ---- dispatch 1: W[k][n] fp32 -> FRAGMENT-ORDERED WtF, 3 matrices ----------
__global__ __launch_bounds__(256) void cvt_w(const float* __restrict__ W0,
                                             const float* __restrict__ W1,
                                             const float* __restrict__ W2,
                                             unsigned int* __restrict__ WtF) {
    const int m = blockIdx.x >> 4;
    const int slice = blockIdx.x & 15;
    const float* W = (m == 0) ? W0 : (m == 1) ? W1 : W2;
    const int ncols = (m == 2) ? 64 : 128;
    unsigned int* dst = WtF + m * 128 * 64;
    const int total = ncols * 64;                  // uints
    for (int idx = slice * 256 + threadIdx.x; idx < total; idx += 16 * 256) {
        const int j    = idx & 3;
        const int lane = (idx >> 2) & 63;
        const int s    = (idx >> 8) & 3;
        const int t    = idx >> 10;
        const int mcol = lane & 15;
        const int quad = lane >> 4;
        const int n = t * 16 + mcol;
        const int k = s * 32 + quad * 8 + 2 * j;
        unsigned int lo = f2bf(W[(size_t)k * ncols + n]);
        unsigned int hi = f2bf(W[(size_t)(k + 1) * ncols + n]);
        dst[idx] = (hi << 16) | lo;
    }
}

// ---- dispatch 2: bf16 MFMA GEMM, 1 wave/block, QUARTERED C-write -----------
__global__ __launch_bounds__(64) void gemm0(const float* __restrict__ feat,
                                            const unsigned int* __restrict__ Wt,
                                            unsigned int* __restrict__ C,
                                            int M) {
    const int lane = threadIdx.x;
    const int row0 = blockIdx.x * 16;
    const int quad = lane >> 4;
    const int mcol = lane & 15;
    const size_t qN = (size_t)M * 16;

    constexpr int NT = 8;
    floatx4 acc[NT];
    #pragma unroll
    for (int t = 0; t < NT; ++t) acc[t] = (floatx4){0.f, 0.f, 0.f, 0.f};

    int aidx = row0 + mcol; if (aidx >= M) aidx = M - 1;
    const float*        arowF = feat + (size_t)aidx * 128 + quad * 8;
    const unsigned int* bbase = Wt + lane * 4;

    #pragma unroll
    for (int s = 0; s < 4; ++s) {
        float4 fa = *(const float4*)(arowF + s * 32);
        float4 fb = *(const float4*)(arowF + s * 32 + 4);
        uintx4 ap;
        ap.x = (f2bf(fa.y) << 16) | f2bf(fa.x);
        ap.y = (f2bf(fa.w) << 16) | f2bf(fa.z);
        ap.z = (f2bf(fb.y) << 16) | f2bf(fb.x);
        ap.w = (f2bf(fb.w) << 16) | f2bf(fb.z);
        bf16x8 a = __builtin_bit_cast(bf16x8, ap);
        #pragma unroll
        for (int t = 0; t < NT; ++t) {
            uintx4 bp = *(const uintx4*)(bbase + t * 1024 + s * 256);
            bf16x8 b = __builtin_bit_cast(bf16x8, bp);
            acc[t] = __builtin_amdgcn_mfma_f32_16x16x32_bf16(a, b, acc[t], 0, 0, 0);
        }
    }

    const int mc2 = mcol >> 1;
    #pragma unroll
    for (int t = 0; t < NT; ++t) {
        #pragma unroll
        for (int r = 0; r < 4; ++r) {
            unsigned int mybf = f2bf(acc[t][r]);
            unsigned int pair = __shfl_xor(mybf, 1, 64);
            int orow = row0 + quad * 4 + r;
            if (orow < M && (mcol & 1) == 0) {
                unsigned int packed = (pair << 16) | mybf;
                const int idx = t * 8 + mc2;                    // uint-in-row 0..63
                C[(size_t)(idx >> 4) * qN + (size_t)orow * 16 + (idx & 15)] = packed;
            }
        }
    }
}

// ---- dispatches 3,4: quartered gather + LN + ReLU -> A-tile -> MFMA x W ----
// Block = 16-node tile, 4 waves x 4 nodes. R15 ping-pong loop run 4x (one
// pass per feature quarter), lane loads 1 uint (4B) per edge per pass.
template <int NCOLS_OUT>
__global__ __launch_bounds__(256) void agg_gemm(const unsigned int* __restrict__ xw,
                                                const int* __restrict__ ptr,
                                                const int* __restrict__ col,
                                                const unsigned int* __restrict__ Wt,
                                                unsigned int* __restrict__ C,
                                                int N, int Emax /* = E-1 */) {
    __shared__ unsigned int lds[1024];           // 16 rows x 128 bf16, A-frag order
    const int tile = blockIdx.x;
    const int wave = threadIdx.x >> 6;
    const int lane = threadIdx.x & 63;
    const int g  = lane >> 4;     // 0..3 edge group
    const int sl = lane & 15;     // 0..15 sublane (owns 1 uint = 2 feats/quarter)
    const size_t qN = (size_t)N * 16;

    int s0[4], len[4];
    int maxlen = 0;
    #pragma unroll
    for (int n = 0; n < 4; ++n) {
        const int node = tile * 16 + wave * 4 + n;
        const int nc = node < N ? node : N - 1;
        const int a = ptr[nc];
        const int b = node < N ? ptr[nc + 1] : a;
        s0[n] = a; len[n] = b - a;
        maxlen = max(maxlen, len[n]);
    }

    float acc[4][8] = {};

    if (maxlen > 0) {
        #define LOADCOL(dst, OFF)                                            \
            _Pragma("unroll")                                                \
            for (int n = 0; n < 4; ++n) {                                    \
                int idx = (OFF) + g;                                         \
                idx = idx < len[n] ? idx : 0;                                \
                int ei = s0[n] + idx;                                        \
                ei = ei < Emax ? ei : Emax;                                  \
                dst[n] = col[ei];                                            \
            }
        #define GATHER1(dst, c)                                              \
            _Pragma("unroll")                                                \
            for (int n = 0; n < 4; ++n)                                      \
                dst[n] = baseq[(size_t)c[n] * 16];
        #define ACCUM1(v, OFF)                                               \
            _Pragma("unroll")                                                \
            for (int n = 0; n < 4; ++n)                                      \
                if ((OFF) + g < len[n]) {                                    \
                    acc[n][2 * q]     += bf_lo(v[n]);                        \
                    acc[n][2 * q + 1] += bf_hi(v[n]);                        \
                }

        #pragma unroll
        for (int q = 0; q < 4; ++q) {
            const unsigned int* baseq = xw + (size_t)q * qN + sl;
            int cA[4], cB[4], cC[4], cD[4];
            unsigned int vA[4], vB[4];
            LOADCOL(cA, 0)
            LOADCOL(cB, 4)
            GATHER1(vA, cA)
            LOADCOL(cC, 8)
            GATHER1(vB, cB)
            LOADCOL(cD, 12)

            const int rounds = (maxlen + 7) & ~7;
            for (int off = 0; off < rounds; off += 8) {
                ACCUM1(vA, off)
                GATHER1(vA, cC)            // data for off+8
                LOADCOL(cC, off + 16)
                ACCUM1(vB, off + 4)
                GATHER1(vB, cD)            // data for off+12
                LOADCOL(cD, off + 20)
            }
        }
        #undef LOADCOL
        #undef GATHER1
        #undef ACCUM1
    }

    // ---- LN + ReLU per node, write LDS A-frag tile (all 64 lanes) ----
    // lane (g,sl) holds feature pair (g*32+sl*2, +1) after the g-reduce.
    #pragma unroll
    for (int n = 0; n < 4; ++n) {
        const int m = wave * 4 + n;
        float a8[8];
        #pragma unroll
        for (int j = 0; j < 8; ++j) {
            float t = acc[n][j];
            t += __shfl_xor(t, 16, 64);
            t += __shfl_xor(t, 32, 64);
            a8[j] = t;
        }
        float s1 = 0.f, s2 = 0.f;
        #pragma unroll
        for (int j = 0; j < 8; ++j) { s1 += a8[j]; s2 += a8[j] * a8[j]; }
        #pragma unroll
        for (int mm = 8; mm >= 1; mm >>= 1) {
            s1 += __shfl_xor(s1, mm, 64);
            s2 += __shfl_xor(s2, mm, 64);
        }
        const float mean = s1 * (1.0f / 128.0f);
        const float var  = s2 * (1.0f / 128.0f) - mean * mean;
        const float inv  = rsqrtf(var + 1e-5f);

        const float e0 = (g == 0) ? a8[0] : (g == 1) ? a8[2] : (g == 2) ? a8[4] : a8[6];
        const float e1 = (g == 0) ? a8[1] : (g == 1) ? a8[3] : (g == 2) ? a8[5] : a8[7];
        const float o0 = fmaxf((e0 - mean) * inv, 0.f);
        const float o1 = fmaxf((e1 - mean) * inv, 0.f);
        lds[g * 256 + (sl >> 2) * 64 + m * 4 + (sl & 3)] = (f2bf(o1) << 16) | f2bf(o0);
    }
    __syncthreads();

    // ---- phase 2: 16 x NCOLS_OUT MFMA, wave covers NCOLS_OUT/4 cols --------
    constexpr int WT = NCOLS_OUT / 64;           // tiles per wave (2 or 1)
    const int quad = lane >> 4;
    const int mcol = lane & 15;
    floatx4 macc[WT];
    #pragma unroll
    for (int t = 0; t < WT; ++t) macc[t] = (floatx4){0.f, 0.f, 0.f, 0.f};

    const unsigned int* bbase = Wt + lane * 4;
    #pragma unroll
    for (int s4 = 0; s4 < 4; ++s4) {
        uintx4 ap = *(const uintx4*)(lds + s4 * 256 + lane * 4);
        bf16x8 a = __builtin_bit_cast(bf16x8, ap);
        #pragma unroll
        for (int tt = 0; tt < WT; ++tt) {
            const int t = wave * WT + tt;
            uintx4 bp = *(const uintx4*)(bbase + t * 1024 + s4 * 256);
            bf16x8 b = __builtin_bit_cast(bf16x8, bp);
            macc[tt] = __builtin_amdgcn_mfma_f32_16x16x32_bf16(a, b, macc[tt], 0, 0, 0);
        }
    }

    // quartered (or halved) C-write: uint-in-row idx -> [idx>>4][row][idx&15]
    const int mc2 = mcol >> 1;
    #pragma unroll
    for (int tt = 0; tt < WT; ++tt) {
        const int t = wave * WT + tt;
        #pragma unroll
        for (int r = 0; r < 4; ++r) {
            unsigned int mybf = f2bf(macc[tt][r]);
            unsigned int pair = __shfl_xor(mybf, 1, 64);
            const int orow = tile * 16 + quad * 4 + r;
            if (orow < N && (mcol & 1) == 0) {
                unsigned int packed = (pair << 16) | mybf;
                const int idx = t * 8 + mc2;
                C[(size_t)(idx >> 4) * qN + (size_t)orow * 16 + (idx & 15)] = packed;
            }
        }
    }
}

// ---- dispatch 5: halved gather + LN, D=64, fp32 out, no ReLU ---------------
__global__ __launch_bounds__(256) void agg_ln64(const unsigned int* __restrict__ xw,
                                                const int* __restrict__ ptr,
                                                const int* __restrict__ col,
                                                float* __restrict__ out,
                                                int N, int Emax) {
    const int tile = blockIdx.x;
    const int wave = threadIdx.x >> 6;
    const int lane = threadIdx.x & 63;
    const int g  = lane >> 4;     // 0..3 edge group
    const int sl = lane & 15;     // 0..15 sublane (1 uint = 2 feats/half)
    const size_t hN = (size_t)N * 16;

    int s0[4], len[4];
    int maxlen = 0;
    #pragma unroll
    for (int n = 0; n < 4; ++n) {
        const int node = tile * 16 + wave * 4 + n;
        const int nc = node < N ? node : N - 1;
        const int a = ptr[nc];
        const int b = node < N ? ptr[nc + 1] : a;
        s0[n] = a; len[n] = b - a;
        maxlen = max(maxlen, len[n]);
    }

    float acc[4][4] = {};

    if (maxlen > 0) {
        #define LOADCOL(dst, OFF)                                            \
            _Pragma("unroll")                                                \
            for (int n = 0; n < 4; ++n) {                                    \
                int idx = (OFF) + g;                                         \
                idx = idx < len[n] ? idx : 0;                                \
                int ei = s0[n] + idx;                                        \
                ei = ei < Emax ? ei : Emax;                                  \
                dst[n] = col[ei];                                            \
            }
        #define GATHER1(dst, c)                                              \
            _Pragma("unroll")                                                \
            for (int n = 0; n < 4; ++n)                                      \
                dst[n] = baseh[(size_t)c[n] * 16];
        #define ACCUM1(v, OFF)                                               \
            _Pragma("unroll")                                                \
            for (int n = 0; n < 4; ++n)                                      \
                if ((OFF) + g < len[n]) {                                    \
                    acc[n][2 * h]     += bf_lo(v[n]);                        \
                    acc[n][2 * h + 1] += bf_hi(v[n]);                        \
                }

        #pragma unroll
        for (int h = 0; h < 2; ++h) {
            const unsigned int* baseh = xw + (size_t)h * hN + sl;
            int cA[4], cB[4], cC[4], cD[4];
            unsigned int vA[4], vB[4];
            LOADCOL(cA, 0)
            LOADCOL(cB, 4)
            GATHER1(vA, cA)
            LOADCOL(cC, 8)
            GATHER1(vB, cB)
            LOADCOL(cD, 12)

            const int rounds = (maxlen + 7) & ~7;
            for (int off = 0; off < rounds; off += 8) {
                ACCUM1(vA, off)
                GATHER1(vA, cC)
                LOADCOL(cC, off + 16)
                ACCUM1(vB, off + 4)
                GATHER1(vB, cD)
                LOADCOL(cD, off + 20)
            }
        }
        #undef LOADCOL
        #undef GATHER1
        #undef ACCUM1
    }

    // lane (g,sl) holds feature pair (h*32+sl*2, +1) for h=g (g<2 writes).
    #pragma unroll
    for (int n = 0; n < 4; ++n) {
        const int node = tile * 16 + wave * 4 + n;
        float a4[4];
        #pragma unroll
        for (int j = 0; j < 4; ++j) {
            float t = acc[n][j];
            t += __shfl_xor(t, 16, 64);
            t += __shfl_xor(t, 32, 64);
            a4[j] = t;
        }
        float s1 = 0.f, s2 = 0.f;
        #pragma unroll
        for (int j = 0; j < 4; ++j) { s1 += a4[j]; s2 += a4[j] * a4[j]; }
        #pragma unroll
        for (int mm = 8; mm >= 1; mm >>= 1) {
            s1 += __shfl_xor(s1, mm, 64);
            s2 += __shfl_xor(s2, mm, 64);
        }
        const float mean = s1 * (1.0f / 64.0f);
        const float var  = s2 * (1.0f / 64.0f) - mean * mean;
        const float inv  = rsqrtf(var + 1e-5f);

        const float e0 = (g == 0) ? a4[0] : a4[2];
        const float e1 = (g == 0) ? a4[1] : a4[3];
        if (g < 2 && node < N) {
            float2 o;
            o.x = (e0 - mean) * inv;
            o.y = (e1 - mean) * inv;
            *(float2*)(out + (size_t)node * 64 + g * 32 + sl * 2) = o;
        }
    }
}

extern "C" void kernel_launch(void* const* d_in, const int* in_sizes, int n_in,
                              void* d_out, int out_size, void* d_ws, size_t ws_size,
                              hipStream_t stream) {
    const float* feat = (const float*)d_in[0];   // [N,128]
    const float* W0   = (const float*)d_in[1];   // [128,128]
    const float* W1   = (const float*)d_in[2];   // [128,128]
    const float* W2   = (const float*)d_in[3];   // [128,64]
    const int*   ptr  = (const int*)d_in[4];     // [N+1]
    const int*   col  = (const int*)d_in[5];     // [E]
    // d_in[6] = edge_rows, unused (CSR ptr encodes the same segments)

    const int N = in_sizes[4] - 1;               // 50000 (= 3125 * 16)
    const int E = in_sizes[5];                   // 800000
    const int Emax = E - 1;

    unsigned int* buf0 = (unsigned int*)d_ws;                // [4][N][16] uint quartered
    unsigned int* buf1 = buf0 + (size_t)N * 64;              // [4][N][16] uint quartered
    unsigned int* WtP  = buf1 + (size_t)N * 64;              // 3 x frag-ordered W
    float*        out  = (float*)d_out;                      // [N,64]

    const int tiles = (N + 15) / 16;             // 3125 (16-node tiles)

    cvt_w<<<48, 256, 0, stream>>>(W0, W1, W2, WtP);
    // Layer 0 GEMM (fp32 feat A-path), quartered C
    gemm0<<<tiles, 64, 0, stream>>>(feat, WtP, buf0, N);
    // Layer 0 agg + LN + ReLU fused with layer 1 GEMM (quartered in+out)
    agg_gemm<128><<<tiles, 256, 0, stream>>>(buf0, ptr, col, WtP + 128 * 64, buf1, N, Emax);
    // Layer 1 agg + LN + ReLU fused with layer 2 GEMM (quartered in, halved out)
    agg_gemm<64><<<tiles, 256, 0, stream>>>(buf1, ptr, col, WtP + 2 * 128 * 64, buf0, N, Emax);
    // Layer 2 agg + LN (no ReLU), halved in, fp32 out
    agg_ln64<<<tiles, 256, 0, stream>>>(buf0, ptr, col, out, N, Emax);
}